// Round 6
// baseline (651.496 us; speedup 1.0000x reference)
//
#include <hip/hip_runtime.h>
#include <cstdint>
#include <cstddef>

typedef __attribute__((ext_vector_type(8))) short short8;
typedef __attribute__((ext_vector_type(4))) float floatx4;
typedef __attribute__((ext_vector_type(16))) float floatx16;

#define SEG 50331648ull   // elements per 100MB bf16 segment (= xb/AO,q,k,v sizes)

__device__ __forceinline__ unsigned short bf16rne(float f) {
  union { float f; unsigned int u; } c; c.f = f;
  unsigned int u = c.u;
  return (unsigned short)((u + 0x7fffu + ((u >> 16) & 1u)) >> 16);
}
__device__ __forceinline__ unsigned int packbf(float a, float b) {
  return (unsigned int)bf16rne(a) | ((unsigned int)bf16rne(b) << 16);
}
__device__ __forceinline__ unsigned int cvtpk(float lo, float hi) {
  unsigned int r;
  asm("v_cvt_pk_bf16_f32 %0, %1, %2" : "=v"(r) : "v"(lo), "v"(hi));
  return r;
}

// ---------------------------------------------------------------------------
// P0: one-time weight prep: qkv_w -> bf16 (q-rows prescaled by 32^-0.5),
// out_w -> bf16, qkv_b -> prescaled fp32 copy.
__global__ __launch_bounds__(256) void w_prep(
    const float* __restrict__ wq, const float* __restrict__ qb,
    const float* __restrict__ ow,
    unsigned short* __restrict__ wqb, unsigned short* __restrict__ owb,
    float* __restrict__ qbs) {
  const float S = 0.17677669529663687f;
  int id = blockIdx.x * 256 + threadIdx.x;   // pair index
  if (id < 55296) {                          // qkv_w: 576*192/2 pairs
    float s = (id < 18432) ? S : 1.0f;       // rows < 192 (q) prescaled
    ((unsigned int*)wqb)[id] = packbf(wq[2 * id] * s, wq[2 * id + 1] * s);
  } else if (id < 55296 + 18432) {           // out_w: 192*192/2 pairs
    int j = id - 55296;
    ((unsigned int*)owb)[j] = packbf(ow[2 * j], ow[2 * j + 1]);
  } else if (id < 55296 + 18432 + 576) {
    int j = id - 55296 - 18432;
    qbs[j] = qb[j] * (j < 192 ? S : 1.0f);
  }
}

// ---------------------------------------------------------------------------
// P1: expand rpe into the SWAPPED (S^T) MFMA 32x32 C/D fragment layout (f32):
// bias_d[head][f=kt2*2+qt2][lane][reg], reg=0..15.  (R4-proven version.)
__global__ void bias_prep(const float* __restrict__ rpe, float* __restrict__ bias_d) {
  const int head = blockIdx.x;
  const int tid = threadIdx.x;
  for (int e = tid; e < 4096; e += 256) {
    int f = e >> 10;              // frag = kt2*2+qt2
    int lane = (e >> 4) & 63;
    int reg = e & 15;
    int kt2 = f >> 1, qt2 = f & 1;
    int qq = qt2 * 32 + (lane & 31);
    int kk = kt2 * 32 + (reg & 3) + 8 * (reg >> 2) + 4 * (lane >> 5);
    int idx = ((kk >> 3) - (qq >> 3) + 7) * 15 + ((kk & 7) - (qq & 7) + 7);
    bias_d[((size_t)(head * 4 + f) * 64 + lane) * 16 + reg] = rpe[head * 225 + idx];
  }
}

// ---------------------------------------------------------------------------
// P2: x[b][c][65536] fp32 -> xb[b][pix][192] bf16 (transpose + convert).
// Standalone on purpose: runs at high occupancy where the strided reads and
// padded-LDS transpose conflicts are TLP-hidden (R3 fusion regressed 65us).
__global__ __launch_bounds__(256) void x_to_bf16(const float* __restrict__ x,
                                                 unsigned short* __restrict__ xb) {
  __shared__ float Tl[64][65];
  const int tid = threadIdx.x;
  const int ptile = blockIdx.x, cc = blockIdx.y, b = blockIdx.z;
  const float* src = x + ((size_t)(b * 192 + cc * 64)) * 65536 + ptile * 64;
  {
    int row = tid >> 2;            // c within chunk
    int cb = (tid & 3) * 4;
#pragma unroll
    for (int rr = 0; rr < 4; ++rr) {
      int col = cb + rr * 16;      // p within tile
      float4 v = *(const float4*)(src + (size_t)row * 65536 + col);
      *(float4*)&Tl[row][col] = v;
    }
  }
  __syncthreads();
  unsigned short* dst = xb + ((size_t)b * 65536 + (size_t)ptile * 64) * 192 + cc * 64;
  {
    int p_l = tid >> 2;
    int c0 = (tid & 3) * 16;
    unsigned int w[8];
#pragma unroll
    for (int e = 0; e < 8; ++e)
      w[e] = cvtpk(Tl[c0 + 2 * e][p_l], Tl[c0 + 2 * e + 1][p_l]);
    *(uint4*)(dst + (size_t)p_l * 192 + c0)     = make_uint4(w[0], w[1], w[2], w[3]);
    *(uint4*)(dst + (size_t)p_l * 192 + c0 + 8) = make_uint4(w[4], w[5], w[6], w[7]);
  }
}

// ---------------------------------------------------------------------------
// Kernel A: qkv = W(576x192) @ xb^T. X panel staged once, 9 o-tiles inside,
// W staged from pre-converted bf16, reg-prefetched one tile ahead.
#define WP 200
#define XP 200
__global__ __launch_bounds__(256) void qkv_mm(
    const unsigned short* __restrict__ xb, const unsigned short* __restrict__ wqb,
    const float* __restrict__ qbs,
    unsigned short* __restrict__ q, unsigned short* __restrict__ k,
    unsigned short* __restrict__ v) {
  __shared__ unsigned short Xl[128 * XP];
  __shared__ unsigned short Wl[64 * WP];
  const int tid = threadIdx.x;
  const int pt = blockIdx.x, b = blockIdx.y;
  const int lane = tid & 63, w = tid >> 6;
  const int n16 = lane & 15, quad = lane >> 4;

  const unsigned short* xrow = xb + ((size_t)b * 65536 + (size_t)pt * 128) * 192;
#pragma unroll
  for (int r = 0; r < 12; ++r) {
    int c = tid + 256 * r;               // chunk id in [0,3072)
    int row = c / 24;
    int col = (c - row * 24) * 8;
    short8 xv = *(const short8*)(xrow + (size_t)c * 8);
    *(short8*)&Xl[row * XP + col] = xv;
  }
  int wrow[6], wcol[6];
#pragma unroll
  for (int r = 0; r < 6; ++r) {
    int id = tid + 256 * r;
    wrow[r] = id / 24;
    wcol[r] = (id - wrow[r] * 24) * 8;
  }
  short8 wpre[6];
#pragma unroll
  for (int r = 0; r < 6; ++r)
    wpre[r] = *(const short8*)(wqb + (size_t)wrow[r] * 192 + wcol[r]);
#pragma unroll
  for (int r = 0; r < 6; ++r)
    *(short8*)&Wl[wrow[r] * WP + wcol[r]] = wpre[r];
  __syncthreads();

  const floatx4 fz = {0.f, 0.f, 0.f, 0.f};
#pragma unroll 1
  for (int ot = 0; ot < 9; ++ot) {
    if (ot < 8) {
      const unsigned short* wn = wqb + (size_t)(ot + 1) * 64 * 192;
#pragma unroll
      for (int r = 0; r < 6; ++r)
        wpre[r] = *(const short8*)(wn + (size_t)wrow[r] * 192 + wcol[r]);
    }
    floatx4 acc[4][2];
#pragma unroll
    for (int i = 0; i < 4; ++i)
#pragma unroll
      for (int j = 0; j < 2; ++j) acc[i][j] = fz;
#pragma unroll
    for (int k0 = 0; k0 < 192; k0 += 32) {
      short8 a[4], bf[2];
#pragma unroll
      for (int i = 0; i < 4; ++i)
        a[i] = *(const short8*)&Wl[(16 * i + n16) * WP + k0 + quad * 8];
#pragma unroll
      for (int j = 0; j < 2; ++j)
        bf[j] = *(const short8*)&Xl[(w * 32 + 16 * j + n16) * XP + k0 + quad * 8];
#pragma unroll
      for (int i = 0; i < 4; ++i)
#pragma unroll
        for (int j = 0; j < 2; ++j)
          acc[i][j] = __builtin_amdgcn_mfma_f32_16x16x32_bf16(a[i], bf[j], acc[i][j], 0, 0, 0);
    }
    __syncthreads();
    if (ot < 8) {
#pragma unroll
      for (int r = 0; r < 6; ++r)
        *(short8*)&Wl[wrow[r] * WP + wcol[r]] = wpre[r];
    }
    __syncthreads();

    const int sel = ot / 3;          // 0:q 1:k 2:v
    unsigned short* dst = (sel == 0) ? q : ((sel == 1) ? k : v);
    const int h = pt >> 1;
    float4 bb[4];
#pragma unroll
    for (int i = 0; i < 4; ++i)
      bb[i] = *(const float4*)(qbs + ot * 64 + 16 * i + quad * 4);
#pragma unroll
    for (int j = 0; j < 2; ++j) {
      int wcol2 = w * 32 + 16 * j + n16;
      int wc = ((pt & 1) << 7) + wcol2;
      int win = (b << 10) + (h >> 3) * 32 + (wc >> 3);
      int t = ((h & 7) << 3) + (wc & 7);
#pragma unroll
      for (int i = 0; i < 4; ++i) {
        int og = ot * 64 + 16 * i + quad * 4;
        int off = og - sel * 192;
        int head = off >> 5, c = off & 31;
        *(uint2*)(dst + ((size_t)(win * 6 + head) * 64 + t) * 32 + c) =
            make_uint2(cvtpk(acc[i][j][0] + bb[i].x, acc[i][j][1] + bb[i].y),
                       cvtpk(acc[i][j][2] + bb[i].z, acc[i][j][3] + bb[i].w));
      }
    }
  }
}

// ---------------------------------------------------------------------------
// Kernel B: window attention. One wave handles 4 consecutive windows of ONE
// head (head = blockIdx>>8, exactly block-uniform). The head's f32 bias table
// (16 KB) is staged into LDS once per block — kills the 16 KB/wave L2 bias
// re-reads that dominated R4's attn traffic. Per-window math is R4-verbatim
// (f32 bias, swapped S^T, in-register P via cvt_pk+permlane32_swap); the
// 4-window loop is fully unrolled so the compiler hoists next-window loads.
__global__ __launch_bounds__(256) void attn(
    const unsigned short* __restrict__ q, const unsigned short* __restrict__ k,
    const unsigned short* __restrict__ v, const float* __restrict__ bias_d,
    unsigned short* __restrict__ AO) {
  __shared__ unsigned short vl[4][32 * 72];   // per-wave V^T [c][t], pad 72
  __shared__ float4 bl[16 * 64];              // bias [f*4+g][lane] (16 KB)
  const int tid = threadIdx.x, w = tid >> 6, lane = tid & 63;
  const int m32 = lane & 31, half = lane >> 5;
  const int head = blockIdx.x >> 8;           // 256 blocks per head
  const int gw = blockIdx.x * 4 + w;
  const int win0 = (gw & 1023) << 2;          // 4 consecutive windows

  {  // cooperative stage: src f4 idx s = (f*64+ln)*4+g -> dst (f*4+g)*64+ln
    const float4* src = (const float4*)(bias_d + (size_t)head * 4096);
    for (int s = tid; s < 1024; s += 256) {
      int f = s >> 8, ln = (s >> 2) & 63, g = s & 3;
      bl[(f * 4 + g) * 64 + ln] = src[s];
    }
  }
  __syncthreads();

  unsigned short* vlw = (unsigned short*)vl[w];
  const floatx16 fz16 = {0.f,0.f,0.f,0.f,0.f,0.f,0.f,0.f,0.f,0.f,0.f,0.f,0.f,0.f,0.f,0.f};

#pragma unroll
  for (int wi = 0; wi < 4; ++wi) {
    const int win = win0 + wi;
    const size_t base = ((size_t)win * 6 + head) * 2048;
    const unsigned short* qb = q + base;
    const unsigned short* kb = k + base;
    const unsigned short* vb = v + base;

    short8 vrow[4];
#pragma unroll
    for (int c8 = 0; c8 < 4; ++c8)
      vrow[c8] = *(const short8*)(vb + lane * 32 + c8 * 8);

    short8 ka[2][2];
#pragma unroll
    for (int kt2 = 0; kt2 < 2; ++kt2)
#pragma unroll
      for (int cc = 0; cc < 2; ++cc)
        ka[kt2][cc] = *(const short8*)(kb + (size_t)(kt2 * 32 + m32) * 32 + cc * 16 + half * 8);

#pragma unroll
    for (int c8 = 0; c8 < 4; ++c8)
#pragma unroll
      for (int e = 0; e < 8; ++e)
        vlw[(c8 * 8 + e) * 72 + lane] = (unsigned short)vrow[c8][e];

    short8 va[4];
#pragma unroll
    for (int k16 = 0; k16 < 4; ++k16)
      va[k16] = *(const short8*)&vlw[m32 * 72 + k16 * 16 + half * 8];

#pragma unroll
    for (int qt2 = 0; qt2 < 2; ++qt2) {
      float4 bb[8];
#pragma unroll
      for (int g = 0; g < 4; ++g) bb[g] = bl[(qt2 * 4 + g) * 64 + lane];
#pragma unroll
      for (int g = 0; g < 4; ++g) bb[4 + g] = bl[((2 + qt2) * 4 + g) * 64 + lane];

      short8 qf0 = *(const short8*)(qb + (size_t)(qt2 * 32 + m32) * 32 + half * 8);
      short8 qf1 = *(const short8*)(qb + (size_t)(qt2 * 32 + m32) * 32 + 16 + half * 8);

      floatx16 st0 = __builtin_amdgcn_mfma_f32_32x32x16_bf16(ka[0][0], qf0, fz16, 0, 0, 0);
      st0 = __builtin_amdgcn_mfma_f32_32x32x16_bf16(ka[0][1], qf1, st0, 0, 0, 0);
      floatx16 st1 = __builtin_amdgcn_mfma_f32_32x32x16_bf16(ka[1][0], qf0, fz16, 0, 0, 0);
      st1 = __builtin_amdgcn_mfma_f32_32x32x16_bf16(ka[1][1], qf1, st1, 0, 0, 0);

      float x[32];
#pragma unroll
      for (int r = 0; r < 16; ++r) x[r]      = st0[r] + ((const float*)&bb[r >> 2])[r & 3];
#pragma unroll
      for (int r = 0; r < 16; ++r) x[16 + r] = st1[r] + ((const float*)&bb[4 + (r >> 2)])[r & 3];

      // tree max (depth 5) + cross-half
      float t16[16];
#pragma unroll
      for (int r = 0; r < 16; ++r) t16[r] = fmaxf(x[r], x[r + 16]);
#pragma unroll
      for (int r = 0; r < 8; ++r) t16[r] = fmaxf(t16[r], t16[r + 8]);
#pragma unroll
      for (int r = 0; r < 4; ++r) t16[r] = fmaxf(t16[r], t16[r + 4]);
      float mx = fmaxf(fmaxf(t16[0], t16[1]), fmaxf(t16[2], t16[3]));
      mx = fmaxf(mx, __shfl_xor(mx, 32));

#pragma unroll
      for (int r = 0; r < 32; ++r) x[r] = __expf(x[r] - mx);
      float s16[16];
#pragma unroll
      for (int r = 0; r < 16; ++r) s16[r] = x[r] + x[r + 16];
#pragma unroll
      for (int r = 0; r < 8; ++r) s16[r] += s16[r + 8];
#pragma unroll
      for (int r = 0; r < 4; ++r) s16[r] += s16[r + 4];
      float s = (s16[0] + s16[1]) + (s16[2] + s16[3]);
      s += __shfl_xor(s, 32);
      float iv = 1.0f / s;          // normalization deferred to O

      unsigned int u[16];
#pragma unroll
      for (int j = 0; j < 16; ++j) u[j] = cvtpk(x[2 * j], x[2 * j + 1]);

      floatx16 o = fz16;
#pragma unroll
      for (int k16 = 0; k16 < 4; ++k16) {
        int ub = (k16 >> 1) * 8 + (k16 & 1) * 4;
        unsigned int a0 = u[ub + 0], b0 = u[ub + 2];
        unsigned int a1 = u[ub + 1], b1 = u[ub + 3];
        asm("v_permlane32_swap_b32 %0, %1" : "+v"(a0), "+v"(b0));
        asm("v_permlane32_swap_b32 %0, %1" : "+v"(a1), "+v"(b1));
        union { unsigned int wd[4]; short8 s8; } bw;
        bw.wd[0] = a0; bw.wd[1] = a1; bw.wd[2] = b0; bw.wd[3] = b1;
        o = __builtin_amdgcn_mfma_f32_32x32x16_bf16(va[k16], bw.s8, o, 0, 0, 0);
      }

      const int t = qt2 * 32 + m32;
      const int bimg = win >> 10, rem = win & 1023;
      const int h0 = (rem >> 5) << 3, w0 = (rem & 31) << 3;
      const size_t pix = ((size_t)bimg << 16) + (size_t)(h0 + (t >> 3)) * 256 + w0 + (t & 7);
      unsigned short* dstp = AO + pix * 192 + head * 32 + half * 4;
#pragma unroll
      for (int g = 0; g < 4; ++g) {
        float v0 = o[4 * g + 0] * iv, v1 = o[4 * g + 1] * iv;
        float v2 = o[4 * g + 2] * iv, v3 = o[4 * g + 3] * iv;
        *(uint2*)(dstp + g * 8) = make_uint2(cvtpk(v0, v1), cvtpk(v2, v3));
      }
    }
  }
}

// ---------------------------------------------------------------------------
// Kernel C: out = W2(192x192) @ AO^T. A=AO (m=p), B=W2 (n=o) -> D[p][o].
__global__ __launch_bounds__(256) void out_mm(
    const unsigned short* __restrict__ AO, const unsigned short* __restrict__ owb,
    const float* __restrict__ b2, float* __restrict__ out) {
  __shared__ unsigned short Xl[128 * XP];
  __shared__ unsigned short Wl[64 * WP];
  const int tid = threadIdx.x;
  const int pt = blockIdx.x, b = blockIdx.y;
  const int lane = tid & 63, w = tid >> 6;
  const int n16 = lane & 15, quad = lane >> 4;

  const unsigned short* arow = AO + ((size_t)b * 65536 + (size_t)pt * 128) * 192;
#pragma unroll
  for (int r = 0; r < 12; ++r) {
    int c = tid + 256 * r;
    int row = c / 24;
    int col = (c - row * 24) * 8;
    short8 xv = *(const short8*)(arow + (size_t)c * 8);
    *(short8*)&Xl[row * XP + col] = xv;
  }
  int wrow[6], wcol[6];
#pragma unroll
  for (int r = 0; r < 6; ++r) {
    int id = tid + 256 * r;
    wrow[r] = id / 24;
    wcol[r] = (id - wrow[r] * 24) * 8;
  }
  short8 wpre[6];
#pragma unroll
  for (int r = 0; r < 6; ++r)
    wpre[r] = *(const short8*)(owb + (size_t)wrow[r] * 192 + wcol[r]);
#pragma unroll
  for (int r = 0; r < 6; ++r)
    *(short8*)&Wl[wrow[r] * WP + wcol[r]] = wpre[r];
  __syncthreads();

  const floatx4 fz = {0.f, 0.f, 0.f, 0.f};
#pragma unroll 1
  for (int ot = 0; ot < 3; ++ot) {
    if (ot < 2) {
      const unsigned short* wn = owb + (size_t)(ot + 1) * 64 * 192;
#pragma unroll
      for (int r = 0; r < 6; ++r)
        wpre[r] = *(const short8*)(wn + (size_t)wrow[r] * 192 + wcol[r]);
    }
    floatx4 acc[2][4];
#pragma unroll
    for (int i = 0; i < 2; ++i)
#pragma unroll
      for (int j = 0; j < 4; ++j) acc[i][j] = fz;
#pragma unroll
    for (int k0 = 0; k0 < 192; k0 += 32) {
      short8 a[2], bf[4];
#pragma unroll
      for (int i = 0; i < 2; ++i)
        a[i] = *(const short8*)&Xl[(w * 32 + 16 * i + n16) * XP + k0 + quad * 8];
#pragma unroll
      for (int j = 0; j < 4; ++j)
        bf[j] = *(const short8*)&Wl[(16 * j + n16) * WP + k0 + quad * 8];
#pragma unroll
      for (int i = 0; i < 2; ++i)
#pragma unroll
        for (int j = 0; j < 4; ++j)
          acc[i][j] = __builtin_amdgcn_mfma_f32_16x16x32_bf16(a[i], bf[j], acc[i][j], 0, 0, 0);
    }
    __syncthreads();
    if (ot < 2) {
#pragma unroll
      for (int r = 0; r < 6; ++r)
        *(short8*)&Wl[wrow[r] * WP + wcol[r]] = wpre[r];
    }
    __syncthreads();

#pragma unroll
    for (int j = 0; j < 4; ++j) {
      int o = ot * 64 + 16 * j + n16;
      float bj = b2[o];
      float* obase = out + ((size_t)b * 192 + o) * 65536 + (size_t)pt * 128;
#pragma unroll
      for (int i = 0; i < 2; ++i) {
        int p = w * 32 + 16 * i + quad * 4;
        *(float4*)(obase + p) = make_float4(acc[i][j][0] + bj, acc[i][j][1] + bj,
                                            acc[i][j][2] + bj, acc[i][j][3] + bj);
      }
    }
  }
}

// ---------------------------------------------------------------------------
extern "C" void kernel_launch(void* const* d_in, const int* in_sizes, int n_in,
                              void* d_out, int out_size, void* d_ws, size_t ws_size,
                              hipStream_t stream) {
  const float* x     = (const float*)d_in[0];
  const float* qkv_w = (const float*)d_in[1];
  const float* qkv_b = (const float*)d_in[2];
  const float* out_w = (const float*)d_in[3];
  const float* out_b = (const float*)d_in[4];
  const float* rpe   = (const float*)d_in[5];
  float* out = (float*)d_out;

  // Segment plan:
  //   seg0: xb, later reused as AO (disjoint lifetimes)
  //   seg1..3: q, k, v
  //   seg4: prepped weights + f32 bias table
  unsigned short* xb = (unsigned short*)d_ws;
  unsigned short* AO = xb;
  unsigned short* q  = xb + SEG;
  unsigned short* k  = q + SEG;
  unsigned short* v  = k + SEG;
  unsigned short* wqb = v + SEG;                     // 576*192 bf16
  unsigned short* owb = wqb + 110592;                // 192*192 bf16
  float* qbs = (float*)(owb + 36864);                // 576 fp32 (16B-aligned)
  float* bias_d = qbs + 576;                         // 6*4096 fp32 (16B-aligned)

  w_prep<<<291, 256, 0, stream>>>(qkv_w, qkv_b, out_w, wqb, owb, qbs);
  bias_prep<<<6, 256, 0, stream>>>(rpe, bias_d);
  x_to_bf16<<<dim3(1024, 3, 4), 256, 0, stream>>>(x, xb);
  qkv_mm<<<dim3(512, 4), 256, 0, stream>>>(xb, wqb, qbs, q, k, v);
  attn<<<1536, 256, 0, stream>>>(q, k, v, bias_d, AO);
  out_mm<<<dim3(512, 4), 256, 0, stream>>>(AO, owb, out_b, out);
}